// Round 10
// baseline (8046.942 us; speedup 1.0000x reference)
//
#include <hip/hip_runtime.h>
#include <hip/hip_bf16.h>
#include <math.h>

#define BATCH 16
#define C_IN 8
#define C_MID 64
#define C_OUT 128
#define LEN 512
#define TSTEPS 50
#define HZN 8
#define TL 16    // l-tile for encoders
#define RTL 8    // l-tile for rnn_step (1024 blocks -> 4 blocks/CU)

// ---------------------------------------------------------------------------
// Tiled encoder conv1d (k=3, same-pad) + activation, fp32.
// Block: 256 threads, covers (b, all Cout, TL=16 l).
// ---------------------------------------------------------------------------
template <int Ci, int Cout, int ACT>
__global__ __launch_bounds__(256)
void enc_conv(const float* __restrict__ x, const float* __restrict__ w,
              const float* __restrict__ bias, float* __restrict__ y) {
    constexpr int OPT = Cout / 64;   // o's per thread (1 or 2)
    const int l0 = blockIdx.x * TL;
    const int b  = blockIdx.y;
    const int tid = threadIdx.x;
    const int lt = tid & 3;
    const int o0 = (tid >> 2) * OPT;

    __shared__ float xs[Ci][TL + 2];
    for (int k = tid; k < Ci * (TL + 2); k += 256) {
        const int i = k / (TL + 2);
        const int j = k - i * (TL + 2);
        const int gl = l0 + j - 1;
        const bool ok = (gl >= 0) && (gl < LEN);
        xs[i][j] = ok ? x[((size_t)b * Ci + i) * LEN + gl] : 0.f;
    }
    __syncthreads();

    float acc[OPT][4];
    #pragma unroll
    for (int oo = 0; oo < OPT; ++oo) {
        const float bv = bias[o0 + oo];
        #pragma unroll
        for (int ll = 0; ll < 4; ++ll) acc[oo][ll] = bv;
    }

    const int lb = lt * 4;
    #pragma unroll 4
    for (int i = 0; i < Ci; ++i) {
        float xv[6];
        #pragma unroll
        for (int c = 0; c < 6; ++c) xv[c] = xs[i][lb + c];
        #pragma unroll
        for (int oo = 0; oo < OPT; ++oo) {
            const float* wp = &w[((o0 + oo) * Ci + i) * 3];
            const float w0 = wp[0], w1 = wp[1], w2 = wp[2];
            #pragma unroll
            for (int ll = 0; ll < 4; ++ll)
                acc[oo][ll] += w0 * xv[ll] + w1 * xv[ll + 1] + w2 * xv[ll + 2];
        }
    }

    #pragma unroll
    for (int oo = 0; oo < OPT; ++oo) {
        #pragma unroll
        for (int ll = 0; ll < 4; ++ll) {
            float v = acc[oo][ll];
            if (ACT == 1) v = v > 0.f ? v : 0.f;
            else if (ACT == 2) v = tanhf(v);
            y[((size_t)b * Cout + o0 + oo) * LEN + l0 + lb + ll] = v;
        }
    }
}

__global__ void zero_f32(float* __restrict__ p, int n) {
    int i = blockIdx.x * 256 + threadIdx.x;
    if (i < n) p[i] = 0.f;
}

// ---------------------------------------------------------------------------
// One coRNN step, fp32.  RTL=8 l-tile -> grid 64x16=1024 blocks (4 blocks/CU,
// 16 waves/CU = 4 waves/SIMD for latency hiding; round-8 lesson: waves first).
// Thread: l = tid&7, o0 = (tid>>3)*4  (4 o's x 1 l).
// Weights: i-chunked by 4 -> 3 x float4 per (o,conv) per chunk (16B-aligned
// since (o*128+ic)*3*4B is 16-divisible for ic%4==0). 4x fewer VMEM insts.
// LDS: hy/hz [128][RTL+2] fp32 = 10.2 KB.
// Accumulation order per output identical to round 9 (i ascending, same expr).
// ---------------------------------------------------------------------------
__global__ __launch_bounds__(256, 4)
void rnn_step(const float* __restrict__ hy, const float* __restrict__ hz,
              const float* __restrict__ om, const float* __restrict__ al,
              const float* __restrict__ xd,
              const float* __restrict__ wy, const float* __restrict__ by,
              const float* __restrict__ wz, const float* __restrict__ bz,
              float* __restrict__ hyo, float* __restrict__ hzo,
              float* __restrict__ yseq, int t) {
    const int l0 = blockIdx.x * RTL;
    const int b  = blockIdx.y;
    const int tid = threadIdx.x;
    const int l  = tid & 7;
    const int o0 = (tid >> 3) * 4;
    const size_t base = (size_t)b * C_OUT * LEN;

    __shared__ float hys[C_OUT][RTL + 2];
    __shared__ float hzs[C_OUT][RTL + 2];
    for (int k = tid; k < C_OUT * (RTL + 2); k += 256) {
        const int i = k / (RTL + 2);
        const int j = k - i * (RTL + 2);
        const int gl = l0 + j - 1;
        const bool ok = (gl >= 0) && (gl < LEN);
        const size_t gi = base + (size_t)i * LEN + gl;
        hys[i][j] = ok ? hy[gi] : 0.f;
        hzs[i][j] = ok ? hz[gi] : 0.f;
    }
    __syncthreads();

    float ay[4], az[4];
    #pragma unroll
    for (int oo = 0; oo < 4; ++oo) { ay[oo] = by[o0 + oo]; az[oo] = bz[o0 + oo]; }

    // i-chunks of 4
    #pragma unroll 2
    for (int ic = 0; ic < C_OUT; ic += 4) {
        // state taps for the 4 chunk channels (reused across the 4 o's)
        float hv[4][3], zv[4][3];
        #pragma unroll
        for (int cc = 0; cc < 4; ++cc) {
            #pragma unroll
            for (int c = 0; c < 3; ++c) {
                hv[cc][c] = hys[ic + cc][l + c];
                zv[cc][c] = hzs[ic + cc][l + c];
            }
        }
        #pragma unroll
        for (int oo = 0; oo < 4; ++oo) {
            const int o = o0 + oo;
            const float4* wy4 = reinterpret_cast<const float4*>(&wy[((size_t)o * C_OUT + ic) * 3]);
            const float4* wz4 = reinterpret_cast<const float4*>(&wz[((size_t)o * C_OUT + ic) * 3]);
            const float4 a0 = wy4[0], a1 = wy4[1], a2 = wy4[2];
            const float4 c0 = wz4[0], c1 = wz4[1], c2 = wz4[2];
            // i = ic+0: a0.x a0.y a0.z | ic+1: a0.w a1.x a1.y
            // i = ic+2: a1.z a1.w a2.x | ic+3: a2.y a2.z a2.w
            ay[oo] += a0.x * hv[0][0] + a0.y * hv[0][1] + a0.z * hv[0][2];
            az[oo] += c0.x * zv[0][0] + c0.y * zv[0][1] + c0.z * zv[0][2];
            ay[oo] += a0.w * hv[1][0] + a1.x * hv[1][1] + a1.y * hv[1][2];
            az[oo] += c0.w * zv[1][0] + c1.x * zv[1][1] + c1.y * zv[1][2];
            ay[oo] += a1.z * hv[2][0] + a1.w * hv[2][1] + a2.x * hv[2][2];
            az[oo] += c1.z * zv[2][0] + c1.w * zv[2][1] + c2.x * zv[2][2];
            ay[oo] += a2.y * hv[3][0] + a2.z * hv[3][1] + a2.w * hv[3][2];
            az[oo] += c2.y * zv[3][0] + c2.z * zv[3][1] + c2.w * zv[3][2];
        }
    }

    #pragma unroll
    for (int oo = 0; oo < 4; ++oo) {
        const int o = o0 + oo;
        const int gl = l0 + l;
        const size_t idx = base + (size_t)o * LEN + gl;
        const float hyv = hys[o][l + 1];
        const float hzv = hzs[o][l + 1];
        const float pre = tanhf(ay[oo] + az[oo] + xd[idx]);
        const float hzn = hzv + 0.5f * (pre - om[idx] * hyv - al[idx] * hzv);
        const float hyn = hyv + 0.5f * hzn;
        hzo[idx] = hzn;
        hyo[idx] = hyn;
        yseq[((size_t)(b * TSTEPS + t) * C_OUT + o) * LEN + gl] = hyn;
    }
}

// ---------------------------------------------------------------------------
// Readout: feat = mean_L(hy_T); 3-layer MLP (fp64 accum over fp32 data).
// ---------------------------------------------------------------------------
__global__ void readout(const float* __restrict__ hyT,
                        const float* __restrict__ fw1, const float* __restrict__ fb1,
                        const float* __restrict__ fw2, const float* __restrict__ fb2,
                        const float* __restrict__ fw3, const float* __restrict__ fb3,
                        float* __restrict__ pred) {
    const int b = blockIdx.x;
    const int t = threadIdx.x;  // 128 threads
    __shared__ double feat[C_OUT];
    __shared__ double h1[64];
    __shared__ double h2[32];

    {
        double s = 0.0;
        const float* p = &hyT[((size_t)b * C_OUT + t) * LEN];
        for (int l = 0; l < LEN; ++l) s += (double)p[l];
        feat[t] = s * (1.0 / LEN);
    }
    __syncthreads();
    if (t < 64) {
        double s = (double)fb1[t];
        for (int i = 0; i < C_OUT; ++i) s += (double)fw1[t * C_OUT + i] * feat[i];
        h1[t] = s > 0.0 ? s : 0.0;
    }
    __syncthreads();
    if (t < 32) {
        double s = (double)fb2[t];
        for (int i = 0; i < 64; ++i) s += (double)fw2[t * 64 + i] * h1[i];
        h2[t] = s > 0.0 ? s : 0.0;
    }
    __syncthreads();
    if (t < HZN) {
        double s = (double)fb3[t];
        for (int i = 0; i < 32; ++i) s += (double)fw3[t * 32 + i] * h2[i];
        pred[b * HZN + t] = (float)s;
    }
}

// ---------------------------------------------------------------------------
extern "C" void kernel_launch(void* const* d_in, const int* in_sizes, int n_in,
                              void* d_out, int out_size, void* d_ws, size_t ws_size,
                              hipStream_t stream) {
    const float* x   = (const float*)d_in[0];
    const float* ow1 = (const float*)d_in[1];  const float* ob1 = (const float*)d_in[2];
    const float* ow2 = (const float*)d_in[3];  const float* ob2 = (const float*)d_in[4];
    const float* ow3 = (const float*)d_in[5];  const float* ob3 = (const float*)d_in[6];
    const float* aw1 = (const float*)d_in[7];  const float* ab1 = (const float*)d_in[8];
    const float* aw2 = (const float*)d_in[9];  const float* ab2 = (const float*)d_in[10];
    const float* aw3 = (const float*)d_in[11]; const float* ab3 = (const float*)d_in[12];
    const float* hw1 = (const float*)d_in[13]; const float* hb1 = (const float*)d_in[14];
    const float* hw2 = (const float*)d_in[15]; const float* hb2 = (const float*)d_in[16];
    const float* hw3 = (const float*)d_in[17]; const float* hb3 = (const float*)d_in[18];
    const float* hw4 = (const float*)d_in[19]; const float* hb4 = (const float*)d_in[20];
    const float* cwy = (const float*)d_in[21]; const float* cby = (const float*)d_in[22];
    const float* cwz = (const float*)d_in[23]; const float* cbz = (const float*)d_in[24];
    const float* cwx = (const float*)d_in[25]; const float* cbx = (const float*)d_in[26];
    const float* fw1 = (const float*)d_in[27]; const float* fb1 = (const float*)d_in[28];
    const float* fw2 = (const float*)d_in[29]; const float* fb2 = (const float*)d_in[30];
    const float* fw3 = (const float*)d_in[31]; const float* fb3 = (const float*)d_in[32];

    float* out  = (float*)d_out;
    float* pred = out;                    // (B, HZN) fp32
    float* yseq = out + BATCH * HZN;      // (B, T, C_OUT, LEN) fp32

    // workspace: 7 fp32 state buffers (4 MB each = 28 MB total).
    const size_t SZ = (size_t)BATCH * C_OUT * LEN;  // 1,048,576 elements
    float* ws  = (float*)d_ws;
    float* om  = ws + 0 * SZ;
    float* al  = ws + 1 * SZ;
    float* xd  = ws + 2 * SZ;
    float* hyA = ws + 3 * SZ;
    float* hzA = ws + 4 * SZ;
    float* hyB = ws + 5 * SZ;
    float* hzB = ws + 6 * SZ;
    float* t1  = hyB;  // (B, C_MID, L) = 2 MB, fits in 4 MB
    float* t2  = hzB;

    dim3 egrid(LEN / TL, BATCH);   // (32, 16)
    const int go = (BATCH * C_OUT * LEN + 255) / 256;  // 4096 blocks (zero fill)

    // omega encoder
    enc_conv<C_IN,  C_MID, 1><<<egrid, 256, 0, stream>>>(x,  ow1, ob1, t1);
    enc_conv<C_MID, C_MID, 1><<<egrid, 256, 0, stream>>>(t1, ow2, ob2, t2);
    enc_conv<C_MID, C_OUT, 1><<<egrid, 256, 0, stream>>>(t2, ow3, ob3, om);
    // alpha encoder
    enc_conv<C_IN,  C_MID, 1><<<egrid, 256, 0, stream>>>(x,  aw1, ab1, t1);
    enc_conv<C_MID, C_MID, 1><<<egrid, 256, 0, stream>>>(t1, aw2, ab2, t2);
    enc_conv<C_MID, C_OUT, 1><<<egrid, 256, 0, stream>>>(t2, aw3, ab3, al);
    // hy encoder
    enc_conv<C_IN,  C_MID, 1><<<egrid, 256, 0, stream>>>(x,  hw1, hb1, t1);
    enc_conv<C_MID, C_MID, 1><<<egrid, 256, 0, stream>>>(t1, hw2, hb2, t2);
    enc_conv<C_MID, C_MID, 1><<<egrid, 256, 0, stream>>>(t2, hw3, hb3, t1);
    enc_conv<C_MID, C_OUT, 2><<<egrid, 256, 0, stream>>>(t1, hw4, hb4, hyA);
    // x drive (no activation)
    enc_conv<C_IN,  C_OUT, 0><<<egrid, 256, 0, stream>>>(x, cwx, cbx, xd);
    // hz0 = 0
    zero_f32<<<go, 256, 0, stream>>>(hzA, (int)SZ);

    // recurrence (step 0 overwrites hyB/hzB, which held encoder temps)
    float* hy_cur = hyA; float* hz_cur = hzA;
    float* hy_nxt = hyB; float* hz_nxt = hzB;
    dim3 sgrid(LEN / RTL, BATCH);  // (64, 16) = 1024 blocks
    for (int t = 0; t < TSTEPS; ++t) {
        rnn_step<<<sgrid, 256, 0, stream>>>(hy_cur, hz_cur, om, al, xd,
                                            cwy, cby, cwz, cbz,
                                            hy_nxt, hz_nxt, yseq, t);
        float* sy = hy_cur; hy_cur = hy_nxt; hy_nxt = sy;
        float* sz = hz_cur; hz_cur = hz_nxt; hz_nxt = sz;
    }

    // readout on final hy
    readout<<<BATCH, C_OUT, 0, stream>>>(hy_cur, fw1, fb1, fw2, fb2, fw3, fb3, pred);
}